// Round 1
// baseline (329.997 us; speedup 1.0000x reference)
//
#include <hip/hip_runtime.h>
#include <hip/hip_bf16.h>
#include <cstdint>
#include <cstddef>

// MFMA fragment types (gfx950: V8y operands, V4f accumulator)
typedef __bf16 v8bf __attribute__((ext_vector_type(8)));
typedef float  v4f  __attribute__((ext_vector_type(4)));

__device__ __forceinline__ unsigned short f2bf(float f) {
    unsigned int u = __float_as_uint(f);
    u += 0x7fffu + ((u >> 16) & 1u);   // round-to-nearest-even
    return (unsigned short)(u >> 16);
}
__device__ __forceinline__ float bf2f(unsigned short s) {
    return __uint_as_float(((unsigned int)s) << 16);
}

// ---------------------------------------------------------------------------
// GEMM: C[M,N] = A[M,K] * B[K,N], with B supplied transposed (BT is N x K).
// bf16 inputs, fp32 accumulate. 128x128 tile, 256 threads (4 waves, each 64x64).
// BK=32 (one 16x16x32 MFMA K-step per staging iteration). Register prefetch.
// Layouts (verified per guide):
//   A frag:  a[j]  = A[m = lane&15][k = quad*8 + j]
//   B frag:  b[j]  = B[k = quad*8 + j][n = lane&15] = BT[n][k]
//   C/D:     d[r]  = C[row = quad*4 + r][col = lane&15]
// ---------------------------------------------------------------------------
template<int WRITE_BF16>
__global__ __launch_bounds__(256, 2) void gemm_bt(
    const unsigned short* __restrict__ A,   // M x K, row stride lda (bf16)
    const unsigned short* __restrict__ BT,  // N x K, row stride ldb (bf16)
    void* __restrict__ C,                   // M x N, row stride ldc
    int K, int lda, int ldb, int ldc,
    size_t sAz, size_t sBz, size_t sCz)     // per-blockIdx.z strides (elements)
{
    __shared__ unsigned short sA[128 * 32];
    __shared__ unsigned short sB[128 * 32];

    const unsigned short* Ab = A + (size_t)blockIdx.z * sAz;
    const unsigned short* Bb = BT + (size_t)blockIdx.z * sBz;

    const int tid  = threadIdx.x;
    const int wave = tid >> 6;
    const int lane = tid & 63;
    const int quad = lane >> 4;
    const int l16  = lane & 15;
    const size_t bm = (size_t)blockIdx.x * 128;
    const size_t bn = (size_t)blockIdx.y * 128;
    const int wm = (wave >> 1) * 64;
    const int wn = (wave & 1) * 64;

    // staging: 128x32 bf16 tile = 512 x 16B chunks; thread handles chunks tid, tid+256
    const int ro = tid >> 2;          // 0..63
    const int ko = (tid & 3) << 3;    // 0,8,16,24 (bf16 elements)

    const unsigned short* aptr0 = Ab + (bm + ro)      * (size_t)lda + ko;
    const unsigned short* aptr1 = Ab + (bm + ro + 64) * (size_t)lda + ko;
    const unsigned short* bptr0 = Bb + (bn + ro)      * (size_t)ldb + ko;
    const unsigned short* bptr1 = Bb + (bn + ro + 64) * (size_t)ldb + ko;

    uint4 pa0 = *(const uint4*)(aptr0);
    uint4 pa1 = *(const uint4*)(aptr1);
    uint4 pb0 = *(const uint4*)(bptr0);
    uint4 pb1 = *(const uint4*)(bptr1);

    v4f acc[4][4] = {};

    for (int k0 = 0; k0 < K; k0 += 32) {
        *(uint4*)&sA[(size_t)ro * 32 + ko]        = pa0;
        *(uint4*)&sA[(size_t)(ro + 64) * 32 + ko] = pa1;
        *(uint4*)&sB[(size_t)ro * 32 + ko]        = pb0;
        *(uint4*)&sB[(size_t)(ro + 64) * 32 + ko] = pb1;
        __syncthreads();

        v8bf af[4], bfr[4];
        #pragma unroll
        for (int t = 0; t < 4; t++) {
            af[t]  = *(const v8bf*)&sA[(size_t)(wm + t * 16 + l16) * 32 + quad * 8];
            bfr[t] = *(const v8bf*)&sB[(size_t)(wn + t * 16 + l16) * 32 + quad * 8];
        }

        if (k0 + 32 < K) {  // prefetch next K-tile into registers (overlaps MFMA)
            const int kn = k0 + 32;
            pa0 = *(const uint4*)(aptr0 + kn);
            pa1 = *(const uint4*)(aptr1 + kn);
            pb0 = *(const uint4*)(bptr0 + kn);
            pb1 = *(const uint4*)(bptr1 + kn);
        }

        #pragma unroll
        for (int ti = 0; ti < 4; ti++)
            #pragma unroll
            for (int tj = 0; tj < 4; tj++)
                acc[ti][tj] = __builtin_amdgcn_mfma_f32_16x16x32_bf16(
                    af[ti], bfr[tj], acc[ti][tj], 0, 0, 0);
        __syncthreads();
    }

    // epilogue
    if (WRITE_BF16) {
        unsigned short* Cb = (unsigned short*)C + (size_t)blockIdx.z * sCz;
        #pragma unroll
        for (int ti = 0; ti < 4; ti++) {
            const size_t row0 = bm + wm + ti * 16 + quad * 4;
            #pragma unroll
            for (int tj = 0; tj < 4; tj++) {
                const size_t col = bn + wn + tj * 16 + l16;
                #pragma unroll
                for (int r = 0; r < 4; r++)
                    Cb[(row0 + r) * (size_t)ldc + col] = f2bf(acc[ti][tj][r]);
            }
        }
    } else {
        float* Cb = (float*)C + (size_t)blockIdx.z * sCz;
        #pragma unroll
        for (int ti = 0; ti < 4; ti++) {
            const size_t row0 = bm + wm + ti * 16 + quad * 4;
            #pragma unroll
            for (int tj = 0; tj < 4; tj++) {
                const size_t col = bn + wn + tj * 16 + l16;
                #pragma unroll
                for (int r = 0; r < 4; r++)
                    Cb[(row0 + r) * (size_t)ldc + col] = acc[ti][tj][r];
            }
        }
    }
}

// ---------------------------------------------------------------------------
// Gram: partial[split][bh][c][d] = sum_{n in split} qk[b,n,h*64+c]*qk[b,n,h*64+d]
// qkv is 16384 x 2048 bf16, qk in cols 0..1023. 8 K-splits of 1024 tokens.
// ---------------------------------------------------------------------------
__global__ __launch_bounds__(256) void gram_kernel(
    const unsigned short* __restrict__ qkv,
    float* __restrict__ partial)             // [8][32][64][64]
{
    const int bh = blockIdx.x;               // b*16+h, 0..31
    const int split = blockIdx.y;            // 0..7
    const int b = bh >> 4, h = bh & 15;
    const unsigned short* base = qkv + (size_t)b * 8192 * 2048 + (size_t)h * 64;
    const int n0 = split * 1024;

    __shared__ unsigned short sM[128 * 64];  // 128 tokens x 64 channels
    const int tid = threadIdx.x;
    const int c0 = (tid >> 4) << 2;
    const int d0 = (tid & 15) << 2;
    float acc[4][4] = {};

    for (int chunk = 0; chunk < 8; chunk++) {
        const int nb = n0 + chunk * 128;
        #pragma unroll
        for (int i = 0; i < 4; i++) {
            const int ch = tid + i * 256;            // 0..1023
            const int rr = ch >> 3, kk = (ch & 7) << 3;
            *(uint4*)&sM[(size_t)rr * 64 + kk] =
                *(const uint4*)(base + (size_t)(nb + rr) * 2048 + kk);
        }
        __syncthreads();
        for (int n = 0; n < 128; n++) {
            const ushort4 cu = *(const ushort4*)&sM[(size_t)n * 64 + c0];
            const ushort4 du = *(const ushort4*)&sM[(size_t)n * 64 + d0];
            const float cv[4] = {bf2f(cu.x), bf2f(cu.y), bf2f(cu.z), bf2f(cu.w)};
            const float dv[4] = {bf2f(du.x), bf2f(du.y), bf2f(du.z), bf2f(du.w)};
            #pragma unroll
            for (int i = 0; i < 4; i++)
                #pragma unroll
                for (int j = 0; j < 4; j++)
                    acc[i][j] += cv[i] * dv[j];
        }
        __syncthreads();
    }

    float* outp = partial + ((size_t)split * 32 + bh) * 4096;
    #pragma unroll
    for (int i = 0; i < 4; i++)
        #pragma unroll
        for (int j = 0; j < 4; j++)
            outp[(size_t)(c0 + i) * 64 + d0 + j] = acc[i][j];
}

// ---------------------------------------------------------------------------
// Softmax: one wave per (bh, c) row. logits[d] = (2*dot_cd - dot_cc - dot_dd)
//          / sqrt(N) * tau[h]; softmax over d (64 lanes).
// ---------------------------------------------------------------------------
__global__ __launch_bounds__(256) void softmax_kernel(
    const float* __restrict__ partial,   // [8][32][4096]
    const float* __restrict__ tau,       // [16]
    float* __restrict__ attn)            // [32][64][64]
{
    const int gw = (int)((blockIdx.x * 256 + threadIdx.x) >> 6);  // 0..2047
    const int d = threadIdx.x & 63;
    const int bh = gw >> 6;
    const int c = gw & 63;
    const int h = bh & 15;

    float cd = 0.f, cc = 0.f, dd = 0.f;
    #pragma unroll
    for (int s = 0; s < 8; s++) {
        const float* p = partial + ((size_t)s * 32 + bh) * 4096;
        cd += p[c * 64 + d];
        cc += p[c * 65];
        dd += p[d * 65];
    }
    const float INV_SQRT_N = 0.011048543456039806f;  // 1/sqrt(8192)
    const float logit = (2.f * cd - cc - dd) * INV_SQRT_N * tau[h];

    float m = logit;
    #pragma unroll
    for (int off = 32; off > 0; off >>= 1) m = fmaxf(m, __shfl_xor(m, off, 64));
    const float e = __expf(logit - m);
    float sum = e;
    #pragma unroll
    for (int off = 32; off > 0; off >>= 1) sum += __shfl_xor(sum, off, 64);

    attn[(size_t)bh * 4096 + c * 64 + d] = e / sum;
}

// ---------------------------------------------------------------------------
// WeffT[b][j][h*64+d] = sum_c attn[b,h,c,d] * W_out[h*64+c, j]   (bf16 out)
// One block per (bh, jgroup of 64). K=64 over c.
// ---------------------------------------------------------------------------
__global__ __launch_bounds__(256) void wefft_kernel(
    const float* __restrict__ attn,       // [32][64][64] (c,d)
    const float* __restrict__ Wout,       // [1024][1024] fp32
    unsigned short* __restrict__ weffT)   // [2][1024][1024] bf16 (j, i)
{
    const int bh = blockIdx.x;            // 0..31
    const int jg = blockIdx.y;            // 0..15
    const int b = bh >> 4, h = bh & 15;

    __shared__ float sAttT[64][65];       // [d][c]
    __shared__ float sW[64][65];          // [c][j_local]
    const int tid = threadIdx.x;
    const float* ap = attn + (size_t)bh * 4096;
    const float* wp = Wout + (size_t)(h * 64) * 1024 + jg * 64;
    for (int i = tid; i < 4096; i += 256) {
        const int cc = i >> 6, q = i & 63;
        sAttT[q][cc] = ap[i];                          // transpose attn
        sW[cc][q] = wp[(size_t)cc * 1024 + q];
    }
    __syncthreads();

    const int dd0 = (tid >> 4) << 2;
    const int j0  = (tid & 15) << 2;
    float acc[4][4] = {};
    for (int cc = 0; cc < 64; cc++) {
        float av[4], wv[4];
        #pragma unroll
        for (int i = 0; i < 4; i++) av[i] = sAttT[dd0 + i][cc];
        #pragma unroll
        for (int i = 0; i < 4; i++) wv[i] = sW[cc][j0 + i];
        #pragma unroll
        for (int i = 0; i < 4; i++)
            #pragma unroll
            for (int j = 0; j < 4; j++)
                acc[i][j] += av[i] * wv[j];
    }

    unsigned short* op = weffT + ((size_t)b * 1024 + jg * 64) * 1024 + h * 64;
    #pragma unroll
    for (int i = 0; i < 4; i++)
        #pragma unroll
        for (int j = 0; j < 4; j++)
            op[(size_t)(j0 + j) * 1024 + dd0 + i] = f2bf(acc[i][j]);
}

// ---------------------------------------------------------------------------
// fp32 -> bf16 elementwise (x), and tiled transpose-convert (weights)
// ---------------------------------------------------------------------------
__global__ __launch_bounds__(256) void cvt_x_kernel(
    const float* __restrict__ x, unsigned short* __restrict__ xb)
{
    const size_t i = ((size_t)blockIdx.x * 256 + threadIdx.x) * 4;
    const float4 v = *(const float4*)(x + i);
    ushort4 o;
    o.x = f2bf(v.x); o.y = f2bf(v.y); o.z = f2bf(v.z); o.w = f2bf(v.w);
    *(ushort4*)(xb + i) = o;
}

__global__ void cvt_wT_kernel(const float* __restrict__ W,
                              unsigned short* __restrict__ WT)
{
    __shared__ float s[32][33];
    const int n0 = blockIdx.x * 32;
    const int k0 = blockIdx.y * 32;
    for (int i = threadIdx.y; i < 32; i += 8)
        s[i][threadIdx.x] = W[(size_t)(k0 + i) * 1024 + n0 + threadIdx.x];
    __syncthreads();
    for (int i = threadIdx.y; i < 32; i += 8)
        WT[(size_t)(n0 + i) * 1024 + k0 + threadIdx.x] = f2bf(s[threadIdx.x][i]);
}

// ---------------------------------------------------------------------------
extern "C" void kernel_launch(void* const* d_in, const int* in_sizes, int n_in,
                              void* d_out, int out_size, void* d_ws, size_t ws_size,
                              hipStream_t stream)
{
    (void)in_sizes; (void)n_in; (void)out_size; (void)ws_size;
    const float* x    = (const float*)d_in[0];
    const float* Wqk  = (const float*)d_in[1];
    const float* Wv   = (const float*)d_in[2];
    const float* Wout = (const float*)d_in[3];
    const float* tau  = (const float*)d_in[4];

    // workspace layout (bf16 elements unless noted):
    //   xb   : 16384x1024                (32 MB)   -- dead after GEMM1, reused below
    //   wT   : 2048x1024  ([Wqk|Wv]^T)   ( 4 MB)
    //   qkv  : 16384x2048 (qk | v)       (64 MB)
    unsigned short* xb  = (unsigned short*)d_ws;
    unsigned short* wT  = xb + (size_t)16384 * 1024;
    unsigned short* qkv = wT + (size_t)2048 * 1024;
    // reuse xb region after GEMM1:
    unsigned short* wefT = xb;                                   // 2x1024x1024 bf16 (4 MB)
    float* partial = (float*)(xb + (size_t)2 * 1024 * 1024);     // 8x32x4096 f32   (4 MB)
    float* attn    = partial + (size_t)8 * 32 * 4096;            // 32x4096 f32     (0.5 MB)

    // 1. convert x to bf16
    cvt_x_kernel<<<16384, 256, 0, stream>>>(x, xb);
    // 2. transpose-convert weights: wT[n][k] = W[k][n]; n<1024 from Wqk, else Wv
    cvt_wT_kernel<<<dim3(32, 32), dim3(32, 8), 0, stream>>>(Wqk, wT);
    cvt_wT_kernel<<<dim3(32, 32), dim3(32, 8), 0, stream>>>(Wv, wT + (size_t)1024 * 1024);
    // 3. GEMM1: qkv[16384 x 2048] = x @ [Wqk | Wv], bf16 out
    gemm_bt<1><<<dim3(128, 16, 1), 256, 0, stream>>>(
        xb, wT, (void*)qkv, 1024, 1024, 1024, 2048, 0, 0, 0);
    // 4. per-head Gram partials over 8 token-splits
    gram_kernel<<<dim3(32, 8), 256, 0, stream>>>(qkv, partial);
    // 5. softmax -> attn
    softmax_kernel<<<512, 256, 0, stream>>>(partial, tau, attn);
    // 6. fold attn into W_out: WeffT (bf16, transposed for GEMM2)
    wefft_kernel<<<dim3(32, 16), 256, 0, stream>>>(attn, Wout, wefT);
    // 7. GEMM2: out[b] = v[b] @ Weff[b], fp32 out. blockIdx.z = b.
    gemm_bt<0><<<dim3(64, 8, 2), 256, 0, stream>>>(
        qkv + 1024, wefT, d_out, 1024, 2048, 1024, 1024,
        (size_t)8192 * 2048, (size_t)1024 * 1024, (size_t)8192 * 1024);
}

// Round 2
// 293.407 us; speedup vs baseline: 1.1247x; 1.1247x over previous
//
#include <hip/hip_runtime.h>
#include <hip/hip_bf16.h>
#include <cstdint>
#include <cstddef>

// MFMA fragment types (gfx950: V8y operands, V4f accumulator)
typedef __bf16 v8bf __attribute__((ext_vector_type(8)));
typedef float  v4f  __attribute__((ext_vector_type(4)));

__device__ __forceinline__ unsigned short f2bf(float f) {
    unsigned int u = __float_as_uint(f);
    u += 0x7fffu + ((u >> 16) & 1u);   // round-to-nearest-even
    return (unsigned short)(u >> 16);
}

// async global->LDS, 16B per lane. lds base must be wave-uniform; HW deposits
// lane l's 16B at lds_base + l*16. (CK-style uintptr addrspace casts.)
__device__ __forceinline__ void gload_lds16(const unsigned short* g, unsigned short* l) {
    __builtin_amdgcn_global_load_lds(
        (const __attribute__((address_space(1))) unsigned int*)(uintptr_t)g,
        (__attribute__((address_space(3))) unsigned int*)(uintptr_t)l, 16, 0, 0);
}

// ---------------------------------------------------------------------------
// GEMM: C[M,N] = A[M,K] * B[K,N], B supplied transposed (BT is N x K).
// bf16 in, fp32 accumulate. 128x128 tile, 256 threads (4 waves, each 64x64).
// BK=32. Staging via global_load_lds width=16 (m97 structure).
// grid: x = N-blocks (inner, L2 reuse of A-strip), y = M-blocks, z = batch.
// Layouts (verified):
//   A frag:  a[j] = A[m = lane&15][k = quad*8 + j]
//   B frag:  b[j] = B[k = quad*8 + j][n = lane&15] = BT[n][k]
//   C/D:     d[r] = C[row = quad*4 + r][col = lane&15]
// ---------------------------------------------------------------------------
template<int WRITE_BF16>
__global__ __launch_bounds__(256, 2) void gemm_bt(
    const unsigned short* __restrict__ A,   // M x K, row stride lda (bf16)
    const unsigned short* __restrict__ BT,  // N x K, row stride ldb (bf16)
    void* __restrict__ C,                   // M x N, row stride ldc
    int K, int lda, int ldb, int ldc,
    size_t sAz, size_t sBz, size_t sCz)     // per-blockIdx.z strides (elements)
{
    __shared__ unsigned short sA[128 * 32];
    __shared__ unsigned short sB[128 * 32];

    const unsigned short* Ab = A + (size_t)blockIdx.z * sAz;
    const unsigned short* Bb = BT + (size_t)blockIdx.z * sBz;

    const int tid  = threadIdx.x;
    const int wv   = tid >> 6;
    const int lane = tid & 63;
    const int quad = lane >> 4;
    const int l16  = lane & 15;
    const size_t bm = (size_t)blockIdx.y * 128;
    const size_t bn = (size_t)blockIdx.x * 128;
    const int wm = (wv >> 1) * 64;
    const int wn = (wv & 1) * 64;

    // staging map: thread tid covers LDS bytes [tid*16, tid*16+16) of each
    // half-tile => row ro = tid>>2, col ko = (tid&3)*8. Wave w's 64 lanes are
    // exactly bytes [w*1024, (w+1)*1024) -- contiguous, as global_load_lds needs.
    const int ro = tid >> 2;          // 0..63
    const int ko = (tid & 3) << 3;    // 0,8,16,24 (bf16 elements)

    const unsigned short* aptr0 = Ab + (bm + ro)      * (size_t)lda + ko;
    const unsigned short* aptr1 = Ab + (bm + ro + 64) * (size_t)lda + ko;
    const unsigned short* bptr0 = Bb + (bn + ro)      * (size_t)ldb + ko;
    const unsigned short* bptr1 = Bb + (bn + ro + 64) * (size_t)ldb + ko;

    unsigned short* sA0 = &sA[wv * 512];           // rows 16w..16w+15
    unsigned short* sA1 = &sA[2048 + wv * 512];    // rows 64+16w..
    unsigned short* sB0 = &sB[wv * 512];
    unsigned short* sB1 = &sB[2048 + wv * 512];

    v4f acc[4][4] = {};

    for (int k0 = 0; k0 < K; k0 += 32) {
        gload_lds16(aptr0 + k0, sA0);
        gload_lds16(aptr1 + k0, sA1);
        gload_lds16(bptr0 + k0, sB0);
        gload_lds16(bptr1 + k0, sB1);
        __syncthreads();   // drains vmcnt -> tile visible

        v8bf af[4], bfr[4];
        #pragma unroll
        for (int t = 0; t < 4; t++) {
            af[t]  = *(const v8bf*)&sA[(size_t)(wm + t * 16 + l16) * 32 + quad * 8];
            bfr[t] = *(const v8bf*)&sB[(size_t)(wn + t * 16 + l16) * 32 + quad * 8];
        }

        #pragma unroll
        for (int ti = 0; ti < 4; ti++)
            #pragma unroll
            for (int tj = 0; tj < 4; tj++)
                acc[ti][tj] = __builtin_amdgcn_mfma_f32_16x16x32_bf16(
                    af[ti], bfr[tj], acc[ti][tj], 0, 0, 0);
        __syncthreads();   // protect LDS before next overwrite
    }

    if (WRITE_BF16) {
        unsigned short* Cb = (unsigned short*)C + (size_t)blockIdx.z * sCz;
        #pragma unroll
        for (int ti = 0; ti < 4; ti++) {
            const size_t row0 = bm + wm + ti * 16 + quad * 4;
            #pragma unroll
            for (int tj = 0; tj < 4; tj++) {
                const size_t col = bn + wn + tj * 16 + l16;
                #pragma unroll
                for (int r = 0; r < 4; r++)
                    Cb[(row0 + r) * (size_t)ldc + col] = f2bf(acc[ti][tj][r]);
            }
        }
    } else {
        float* Cb = (float*)C + (size_t)blockIdx.z * sCz;
        #pragma unroll
        for (int ti = 0; ti < 4; ti++) {
            const size_t row0 = bm + wm + ti * 16 + quad * 4;
            #pragma unroll
            for (int tj = 0; tj < 4; tj++) {
                const size_t col = bn + wn + tj * 16 + l16;
                #pragma unroll
                for (int r = 0; r < 4; r++)
                    Cb[(row0 + r) * (size_t)ldc + col] = acc[ti][tj][r];
            }
        }
    }
}

// ---------------------------------------------------------------------------
// Gram via MFMA: partial[split][bh][c][d] = sum_{n in split} M[n][c]*M[n][d],
// M = qk head slice (tokens x 64 ch). Stage transposed sMT[ch][tok] (pad 136)
// so both A (=M^T) and B (=M) fragments are contiguous v8bf reads.
// Block = (bh, split): 1024 tokens, 8 chunks of 128. 4 waves; wave w owns
// C rows [16w,16w+16) x all 64 cols (4 mfma tiles).
// ---------------------------------------------------------------------------
__global__ __launch_bounds__(256) void gram_kernel(
    const unsigned short* __restrict__ qkv,  // 16384 x 2048 bf16
    float* __restrict__ partial)             // [8][32][64][64]
{
    const int bh = blockIdx.x;               // b*16+h
    const int split = blockIdx.y;            // 0..7
    const int b = bh >> 4, h = bh & 15;
    const unsigned short* base = qkv + (size_t)b * 8192 * 2048 + (size_t)h * 64;
    const int n0 = split * 1024;

    __shared__ unsigned short sMT[64 * 136]; // [ch][tok], stride 136 (pad)
    const int tid = threadIdx.x;
    const int wv = tid >> 6, lane = tid & 63, quad = lane >> 4, l16 = lane & 15;

    v4f acc[4] = {};

    for (int chunk = 0; chunk < 8; chunk++) {
        const int nb = n0 + chunk * 128;
        __syncthreads();  // previous chunk's reads done before overwrite
        #pragma unroll
        for (int i = 0; i < 4; i++) {
            const int ch = tid + i * 256;        // 0..1023
            const int tok = ch >> 3;             // 0..127
            const int co = (ch & 7) << 3;        // 0,8,..,56
            union { uint4 v; unsigned short s[8]; } u;
            u.v = *(const uint4*)(base + (size_t)(nb + tok) * 2048 + co);
            #pragma unroll
            for (int j = 0; j < 8; j++)
                sMT[(size_t)(co + j) * 136 + tok] = u.s[j];
        }
        __syncthreads();

        #pragma unroll
        for (int ks = 0; ks < 4; ks++) {        // 32 tokens per MFMA K-step
            const int kb = ks * 32 + quad * 8;
            const v8bf a = *(const v8bf*)&sMT[(size_t)(16 * wv + l16) * 136 + kb];
            #pragma unroll
            for (int t = 0; t < 4; t++) {
                const v8bf bb = *(const v8bf*)&sMT[(size_t)(t * 16 + l16) * 136 + kb];
                acc[t] = __builtin_amdgcn_mfma_f32_16x16x32_bf16(a, bb, acc[t], 0, 0, 0);
            }
        }
    }

    float* outp = partial + ((size_t)split * 32 + bh) * 4096;
    #pragma unroll
    for (int t = 0; t < 4; t++)
        #pragma unroll
        for (int r = 0; r < 4; r++)
            outp[(size_t)(16 * wv + quad * 4 + r) * 64 + t * 16 + l16] = acc[t][r];
}

// ---------------------------------------------------------------------------
// Softmax: one wave per (bh, c) row over d (64 lanes).
// ---------------------------------------------------------------------------
__global__ __launch_bounds__(256) void softmax_kernel(
    const float* __restrict__ partial,   // [8][32][4096]
    const float* __restrict__ tau,       // [16]
    float* __restrict__ attn)            // [32][64][64]
{
    const int gw = (int)((blockIdx.x * 256 + threadIdx.x) >> 6);  // 0..2047
    const int d = threadIdx.x & 63;
    const int bh = gw >> 6;
    const int c = gw & 63;
    const int h = bh & 15;

    float cd = 0.f, cc = 0.f, dd = 0.f;
    #pragma unroll
    for (int s = 0; s < 8; s++) {
        const float* p = partial + ((size_t)s * 32 + bh) * 4096;
        cd += p[c * 64 + d];
        cc += p[c * 65];
        dd += p[d * 65];
    }
    const float INV_SQRT_N = 0.011048543456039806f;  // 1/sqrt(8192)
    const float logit = (2.f * cd - cc - dd) * INV_SQRT_N * tau[h];

    float m = logit;
    #pragma unroll
    for (int off = 32; off > 0; off >>= 1) m = fmaxf(m, __shfl_xor(m, off, 64));
    const float e = __expf(logit - m);
    float sum = e;
    #pragma unroll
    for (int off = 32; off > 0; off >>= 1) sum += __shfl_xor(sum, off, 64);

    attn[(size_t)bh * 4096 + c * 64 + d] = e / sum;
}

// ---------------------------------------------------------------------------
// WeffT[b][j][h*64+d] = sum_c attn[b,h,c,d] * W_out[h*64+c, j]   (bf16 out)
// ---------------------------------------------------------------------------
__global__ __launch_bounds__(256) void wefft_kernel(
    const float* __restrict__ attn,       // [32][64][64] (c,d)
    const float* __restrict__ Wout,       // [1024][1024] fp32
    unsigned short* __restrict__ weffT)   // [2][1024][1024] bf16 (j, i)
{
    const int bh = blockIdx.x;            // 0..31
    const int jg = blockIdx.y;            // 0..15
    const int b = bh >> 4, h = bh & 15;

    __shared__ float sAttT[64][65];       // [d][c]
    __shared__ float sW[64][65];          // [c][j_local]
    const int tid = threadIdx.x;
    const float* ap = attn + (size_t)bh * 4096;
    const float* wp = Wout + (size_t)(h * 64) * 1024 + jg * 64;
    for (int i = tid; i < 4096; i += 256) {
        const int cc = i >> 6, q = i & 63;
        sAttT[q][cc] = ap[i];
        sW[cc][q] = wp[(size_t)cc * 1024 + q];
    }
    __syncthreads();

    const int dd0 = (tid >> 4) << 2;
    const int j0  = (tid & 15) << 2;
    float acc[4][4] = {};
    for (int cc = 0; cc < 64; cc++) {
        float av[4], wvv[4];
        #pragma unroll
        for (int i = 0; i < 4; i++) av[i] = sAttT[dd0 + i][cc];
        #pragma unroll
        for (int i = 0; i < 4; i++) wvv[i] = sW[cc][j0 + i];
        #pragma unroll
        for (int i = 0; i < 4; i++)
            #pragma unroll
            for (int j = 0; j < 4; j++)
                acc[i][j] += av[i] * wvv[j];
    }

    unsigned short* op = weffT + ((size_t)b * 1024 + jg * 64) * 1024 + h * 64;
    #pragma unroll
    for (int i = 0; i < 4; i++)
        #pragma unroll
        for (int j = 0; j < 4; j++)
            op[(size_t)(j0 + j) * 1024 + dd0 + i] = f2bf(acc[i][j]);
}

// ---------------------------------------------------------------------------
// fp32 -> bf16 elementwise (x), and tiled transpose-convert (both weights)
// ---------------------------------------------------------------------------
__global__ __launch_bounds__(256) void cvt_x_kernel(
    const float* __restrict__ x, unsigned short* __restrict__ xb)
{
    const size_t i = ((size_t)blockIdx.x * 256 + threadIdx.x) * 4;
    const float4 v = *(const float4*)(x + i);
    ushort4 o;
    o.x = f2bf(v.x); o.y = f2bf(v.y); o.z = f2bf(v.z); o.w = f2bf(v.w);
    *(ushort4*)(xb + i) = o;
}

__global__ void cvt_wT_kernel(const float* __restrict__ W0,
                              const float* __restrict__ W1,
                              unsigned short* __restrict__ WT)
{
    const float* W = blockIdx.z ? W1 : W0;
    unsigned short* O = WT + (size_t)blockIdx.z * 1024 * 1024;
    __shared__ float s[32][33];
    const int n0 = blockIdx.x * 32;
    const int k0 = blockIdx.y * 32;
    for (int i = threadIdx.y; i < 32; i += 8)
        s[i][threadIdx.x] = W[(size_t)(k0 + i) * 1024 + n0 + threadIdx.x];
    __syncthreads();
    for (int i = threadIdx.y; i < 32; i += 8)
        O[(size_t)(n0 + i) * 1024 + k0 + threadIdx.x] = f2bf(s[threadIdx.x][i]);
}

// ---------------------------------------------------------------------------
extern "C" void kernel_launch(void* const* d_in, const int* in_sizes, int n_in,
                              void* d_out, int out_size, void* d_ws, size_t ws_size,
                              hipStream_t stream)
{
    (void)in_sizes; (void)n_in; (void)out_size; (void)ws_size;
    const float* x    = (const float*)d_in[0];
    const float* Wqk  = (const float*)d_in[1];
    const float* Wv   = (const float*)d_in[2];
    const float* Wout = (const float*)d_in[3];
    const float* tau  = (const float*)d_in[4];

    // workspace layout:
    //   xb   : 16384x1024 bf16 (32 MB)   -- dead after GEMM1, reused below
    //   wT   : 2048x1024 bf16  ( 4 MB)
    //   qkv  : 16384x2048 bf16 (64 MB)
    unsigned short* xb  = (unsigned short*)d_ws;
    unsigned short* wT  = xb + (size_t)16384 * 1024;
    unsigned short* qkv = wT + (size_t)2048 * 1024;
    unsigned short* wefT = xb;                                   // 2x1024x1024 bf16
    float* partial = (float*)(xb + (size_t)2 * 1024 * 1024);     // 8x32x4096 f32
    float* attn    = partial + (size_t)8 * 32 * 4096;            // 32x4096 f32

    cvt_x_kernel<<<16384, 256, 0, stream>>>(x, xb);
    cvt_wT_kernel<<<dim3(32, 32, 2), dim3(32, 8), 0, stream>>>(Wqk, Wv, wT);
    // GEMM1: qkv[16384 x 2048] = x @ [Wqk | Wv]; grid x=N-blocks (16), y=M (128)
    gemm_bt<1><<<dim3(16, 128, 1), 256, 0, stream>>>(
        xb, wT, (void*)qkv, 1024, 1024, 1024, 2048, 0, 0, 0);
    gram_kernel<<<dim3(32, 8), 256, 0, stream>>>(qkv, partial);
    softmax_kernel<<<512, 256, 0, stream>>>(partial, tau, attn);
    wefft_kernel<<<dim3(32, 16), 256, 0, stream>>>(attn, Wout, wefT);
    // GEMM2: out[b] = v[b] @ Weff[b]; grid x=N (8), y=M (64), z=batch
    gemm_bt<0><<<dim3(8, 64, 2), 256, 0, stream>>>(
        qkv + 1024, wefT, d_out, 1024, 2048, 1024, 1024,
        (size_t)8192 * 2048, (size_t)1024 * 1024, (size_t)8192 * 1024);
}

// Round 3
// 280.867 us; speedup vs baseline: 1.1749x; 1.0446x over previous
//
#include <hip/hip_runtime.h>
#include <hip/hip_bf16.h>
#include <cstdint>
#include <cstddef>

// MFMA fragment types (gfx950: V8y operands, V4f accumulator)
typedef __bf16 v8bf __attribute__((ext_vector_type(8)));
typedef float  v4f  __attribute__((ext_vector_type(4)));

__device__ __forceinline__ unsigned short f2bf(float f) {
    unsigned int u = __float_as_uint(f);
    u += 0x7fffu + ((u >> 16) & 1u);   // round-to-nearest-even
    return (unsigned short)(u >> 16);
}

// async global->LDS, 16B per lane. LDS deposit is wave-uniform base + lane*16.
__device__ __forceinline__ void gload_lds16(const unsigned short* g, unsigned short* l) {
    __builtin_amdgcn_global_load_lds(
        (const __attribute__((address_space(1))) unsigned int*)(uintptr_t)g,
        (__attribute__((address_space(3))) unsigned int*)(uintptr_t)l, 16, 0, 0);
}

// ---------------------------------------------------------------------------
// GEMM: C[M,N] = A[M,K] * B[K,N], B supplied transposed (BT is N x K).
// bf16 in, fp32 acc. 128x128 tile, 256 thr (4 waves x 64x64), BK=32,
// global_load_lds width=16 staging.
// XOR swizzle: LDS row r's 16B chunk q lives at slot (q ^ (r&3)). We permute
// each lane's SOURCE pointer (legal: deposit slot is fixed at lane*16, we
// choose what global chunk goes there). Fragment reads un-swizzle. This cuts
// the stride-64B ds_read_b128 conflicts from 8-way to 4-way.
// Layouts (verified): A frag a[j]=A[m=lane&15][k=quad*8+j];
//   B frag b[j]=BT[n=lane&15][k=quad*8+j]; C/D d[r]=C[row=quad*4+r][col=lane&15]
// ---------------------------------------------------------------------------
template<int WRITE_BF16>
__global__ __launch_bounds__(256, 2) void gemm_bt(
    const unsigned short* __restrict__ A,   // M x K, row stride lda (bf16)
    const unsigned short* __restrict__ BT,  // N x K, row stride ldb (bf16)
    void* __restrict__ C,                   // M x N, row stride ldc
    int K, int lda, int ldb, int ldc,
    size_t sAz, size_t sBz, size_t sCz)     // per-blockIdx.z strides (elements)
{
    __shared__ unsigned short sA[128 * 32];
    __shared__ unsigned short sB[128 * 32];

    const unsigned short* Ab = A + (size_t)blockIdx.z * sAz;
    const unsigned short* Bb = BT + (size_t)blockIdx.z * sBz;

    const int tid  = threadIdx.x;
    const int wv   = tid >> 6;
    const int lane = tid & 63;
    const int quad = lane >> 4;
    const int l16  = lane & 15;
    const size_t bm = (size_t)blockIdx.y * 128;
    const size_t bn = (size_t)blockIdx.x * 128;
    const int wm = (wv >> 1) * 64;
    const int wn = (wv & 1) * 64;

    // staging: thread tid -> LDS bytes [tid*16, tid*16+16) => row ro=tid>>2,
    // slot tid&3. Source chunk is XOR-swizzled: ko = ((tid&3) ^ (ro&3))*8.
    const int ro = tid >> 2;                          // 0..63
    const int ko = (((tid & 3) ^ (ro & 3)) << 3);     // swizzled source chunk

    const unsigned short* aptr0 = Ab + (bm + ro)      * (size_t)lda + ko;
    const unsigned short* aptr1 = Ab + (bm + ro + 64) * (size_t)lda + ko;
    const unsigned short* bptr0 = Bb + (bn + ro)      * (size_t)ldb + ko;
    const unsigned short* bptr1 = Bb + (bn + ro + 64) * (size_t)ldb + ko;

    unsigned short* sA0 = &sA[wv * 512];
    unsigned short* sA1 = &sA[2048 + wv * 512];
    unsigned short* sB0 = &sB[wv * 512];
    unsigned short* sB1 = &sB[2048 + wv * 512];

    // fragment read column slot (un-swizzle): row r = ..+l16, r&3 == l16&3
    const int sslot = ((quad ^ (l16 & 3)) << 3);

    v4f acc[4][4] = {};

    for (int k0 = 0; k0 < K; k0 += 32) {
        gload_lds16(aptr0 + k0, sA0);
        gload_lds16(aptr1 + k0, sA1);
        gload_lds16(bptr0 + k0, sB0);
        gload_lds16(bptr1 + k0, sB1);
        __syncthreads();

        v8bf af[4], bfr[4];
        #pragma unroll
        for (int t = 0; t < 4; t++) {
            af[t]  = *(const v8bf*)&sA[(size_t)(wm + t * 16 + l16) * 32 + sslot];
            bfr[t] = *(const v8bf*)&sB[(size_t)(wn + t * 16 + l16) * 32 + sslot];
        }

        #pragma unroll
        for (int ti = 0; ti < 4; ti++)
            #pragma unroll
            for (int tj = 0; tj < 4; tj++)
                acc[ti][tj] = __builtin_amdgcn_mfma_f32_16x16x32_bf16(
                    af[ti], bfr[tj], acc[ti][tj], 0, 0, 0);
        __syncthreads();
    }

    if (WRITE_BF16) {
        unsigned short* Cb = (unsigned short*)C + (size_t)blockIdx.z * sCz;
        #pragma unroll
        for (int ti = 0; ti < 4; ti++) {
            const size_t row0 = bm + wm + ti * 16 + quad * 4;
            #pragma unroll
            for (int tj = 0; tj < 4; tj++) {
                const size_t col = bn + wn + tj * 16 + l16;
                #pragma unroll
                for (int r = 0; r < 4; r++)
                    Cb[(row0 + r) * (size_t)ldc + col] = f2bf(acc[ti][tj][r]);
            }
        }
    } else {
        float* Cb = (float*)C + (size_t)blockIdx.z * sCz;
        #pragma unroll
        for (int ti = 0; ti < 4; ti++) {
            const size_t row0 = bm + wm + ti * 16 + quad * 4;
            #pragma unroll
            for (int tj = 0; tj < 4; tj++) {
                const size_t col = bn + wn + tj * 16 + l16;
                #pragma unroll
                for (int r = 0; r < 4; r++)
                    Cb[(row0 + r) * (size_t)ldc + col] = acc[ti][tj][r];
            }
        }
    }
}

// ---------------------------------------------------------------------------
// Gram via MFMA: partial[split][bh][c][d] = sum_{n in split} M[n][c]*M[n][d],
// M = qk head slice (tokens x 64 ch), qk row stride 1024.
// ---------------------------------------------------------------------------
__global__ __launch_bounds__(256) void gram_kernel(
    const unsigned short* __restrict__ qk,   // 16384 x 1024 bf16
    float* __restrict__ partial)             // [8][32][64][64]
{
    const int bh = blockIdx.x;               // b*16+h
    const int split = blockIdx.y;            // 0..7
    const int b = bh >> 4, h = bh & 15;
    const unsigned short* base = qk + (size_t)b * 8192 * 1024 + (size_t)h * 64;
    const int n0 = split * 1024;

    __shared__ unsigned short sMT[64 * 136]; // [ch][tok], stride 136 (272B, 16B-aligned)
    const int tid = threadIdx.x;
    const int wv = tid >> 6, lane = tid & 63, quad = lane >> 4, l16 = lane & 15;

    v4f acc[4] = {};

    for (int chunk = 0; chunk < 8; chunk++) {
        const int nb = n0 + chunk * 128;
        __syncthreads();
        #pragma unroll
        for (int i = 0; i < 4; i++) {
            const int ch = tid + i * 256;        // 0..1023
            const int tok = ch >> 3;             // 0..127
            const int co = (ch & 7) << 3;        // 0,8,..,56
            union { uint4 v; unsigned short s[8]; } u;
            u.v = *(const uint4*)(base + (size_t)(nb + tok) * 1024 + co);
            #pragma unroll
            for (int j = 0; j < 8; j++)
                sMT[(size_t)(co + j) * 136 + tok] = u.s[j];
        }
        __syncthreads();

        #pragma unroll
        for (int ks = 0; ks < 4; ks++) {
            const int kb = ks * 32 + quad * 8;
            const v8bf a = *(const v8bf*)&sMT[(size_t)(16 * wv + l16) * 136 + kb];
            #pragma unroll
            for (int t = 0; t < 4; t++) {
                const v8bf bb = *(const v8bf*)&sMT[(size_t)(t * 16 + l16) * 136 + kb];
                acc[t] = __builtin_amdgcn_mfma_f32_16x16x32_bf16(a, bb, acc[t], 0, 0, 0);
            }
        }
    }

    float* outp = partial + ((size_t)split * 32 + bh) * 4096;
    #pragma unroll
    for (int t = 0; t < 4; t++)
        #pragma unroll
        for (int r = 0; r < 4; r++)
            outp[(size_t)(16 * wv + quad * 4 + r) * 64 + t * 16 + l16] = acc[t][r];
}

// ---------------------------------------------------------------------------
// Softmax: one wave per (bh, c) row over d (64 lanes).
// ---------------------------------------------------------------------------
__global__ __launch_bounds__(256) void softmax_kernel(
    const float* __restrict__ partial,   // [8][32][4096]
    const float* __restrict__ tau,       // [16]
    float* __restrict__ attn)            // [32][64][64]
{
    const int gw = (int)((blockIdx.x * 256 + threadIdx.x) >> 6);  // 0..2047
    const int d = threadIdx.x & 63;
    const int bh = gw >> 6;
    const int c = gw & 63;
    const int h = bh & 15;

    float cd = 0.f, cc = 0.f, dd = 0.f;
    #pragma unroll
    for (int s = 0; s < 8; s++) {
        const float* p = partial + ((size_t)s * 32 + bh) * 4096;
        cd += p[c * 64 + d];
        cc += p[c * 65];
        dd += p[d * 65];
    }
    const float INV_SQRT_N = 0.011048543456039806f;  // 1/sqrt(8192)
    const float logit = (2.f * cd - cc - dd) * INV_SQRT_N * tau[h];

    float m = logit;
    #pragma unroll
    for (int off = 32; off > 0; off >>= 1) m = fmaxf(m, __shfl_xor(m, off, 64));
    const float e = __expf(logit - m);
    float sum = e;
    #pragma unroll
    for (int off = 32; off > 0; off >>= 1) sum += __shfl_xor(sum, off, 64);

    attn[(size_t)bh * 4096 + c * 64 + d] = e / sum;
}

// ---------------------------------------------------------------------------
// WeffT[b][j][h*64+d] = sum_c attn[b,h,c,d] * W_out[h*64+c, j]   (bf16 out)
// ---------------------------------------------------------------------------
__global__ __launch_bounds__(256) void wefft_kernel(
    const float* __restrict__ attn,       // [32][64][64] (c,d)
    const float* __restrict__ Wout,       // [1024][1024] fp32
    unsigned short* __restrict__ weffT)   // [2][1024][1024] bf16 (j, i)
{
    const int bh = blockIdx.x;            // 0..31
    const int jg = blockIdx.y;            // 0..15
    const int b = bh >> 4, h = bh & 15;

    __shared__ float sAttT[64][65];       // [d][c]
    __shared__ float sW[64][65];          // [c][j_local]
    const int tid = threadIdx.x;
    const float* ap = attn + (size_t)bh * 4096;
    const float* wp = Wout + (size_t)(h * 64) * 1024 + jg * 64;
    for (int i = tid; i < 4096; i += 256) {
        const int cc = i >> 6, q = i & 63;
        sAttT[q][cc] = ap[i];
        sW[cc][q] = wp[(size_t)cc * 1024 + q];
    }
    __syncthreads();

    const int dd0 = (tid >> 4) << 2;
    const int j0  = (tid & 15) << 2;
    float acc[4][4] = {};
    for (int cc = 0; cc < 64; cc++) {
        float av[4], wvv[4];
        #pragma unroll
        for (int i = 0; i < 4; i++) av[i] = sAttT[dd0 + i][cc];
        #pragma unroll
        for (int i = 0; i < 4; i++) wvv[i] = sW[cc][j0 + i];
        #pragma unroll
        for (int i = 0; i < 4; i++)
            #pragma unroll
            for (int j = 0; j < 4; j++)
                acc[i][j] += av[i] * wvv[j];
    }

    unsigned short* op = weffT + ((size_t)b * 1024 + jg * 64) * 1024 + h * 64;
    #pragma unroll
    for (int i = 0; i < 4; i++)
        #pragma unroll
        for (int j = 0; j < 4; j++)
            op[(size_t)(j0 + j) * 1024 + dd0 + i] = f2bf(acc[i][j]);
}

// ---------------------------------------------------------------------------
// fp32 -> bf16 elementwise, and tiled transpose-convert (weights)
// ---------------------------------------------------------------------------
__global__ __launch_bounds__(256) void cvt_x_kernel(
    const float* __restrict__ x, unsigned short* __restrict__ xb)
{
    const size_t i = ((size_t)blockIdx.x * 256 + threadIdx.x) * 4;
    const float4 v = *(const float4*)(x + i);
    ushort4 o;
    o.x = f2bf(v.x); o.y = f2bf(v.y); o.z = f2bf(v.z); o.w = f2bf(v.w);
    *(ushort4*)(xb + i) = o;
}

__global__ void cvt_wT_kernel(const float* __restrict__ W,
                              unsigned short* __restrict__ WT)
{
    __shared__ float s[32][33];
    const int n0 = blockIdx.x * 32;
    const int k0 = blockIdx.y * 32;
    for (int i = threadIdx.y; i < 32; i += 8)
        s[i][threadIdx.x] = W[(size_t)(k0 + i) * 1024 + n0 + threadIdx.x];
    __syncthreads();
    for (int i = threadIdx.y; i < 32; i += 8)
        WT[(size_t)(n0 + i) * 1024 + k0 + threadIdx.x] = f2bf(s[threadIdx.x][i]);
}

// ---------------------------------------------------------------------------
extern "C" void kernel_launch(void* const* d_in, const int* in_sizes, int n_in,
                              void* d_out, int out_size, void* d_ws, size_t ws_size,
                              hipStream_t stream)
{
    (void)in_sizes; (void)n_in; (void)out_size; (void)ws_size;
    const float* x    = (const float*)d_in[0];
    const float* Wqk  = (const float*)d_in[1];
    const float* Wv   = (const float*)d_in[2];
    const float* Wout = (const float*)d_in[3];
    const float* tau  = (const float*)d_in[4];

    // Algebraic restructure: out_b = x_b @ (W_v @ Weff_b).  v is never
    // materialized; pipeline FLOPs 103 -> 73 GF.
    //
    // ws layout (bf16 elements unless noted):
    //   xb     : 16384x1024  bf16 (32 MB)
    //   wqkT   : 1024x1024   bf16 ( 2 MB)  W_qk^T
    //   wvb    : 1024x1024   bf16 ( 2 MB)  W_v (row-major, used as BT)
    //   qk     : 16384x1024  bf16 (32 MB)
    //   partial: 8x32x4096   f32  ( 4 MB)
    //   attn   : 32x4096     f32  (.5 MB)
    //   weffT  : 2x1024x1024 bf16 ( 4 MB)
    //   wfoldT : 2x1024x1024 bf16 ( 4 MB)
    unsigned short* xb     = (unsigned short*)d_ws;
    unsigned short* wqkT   = xb + (size_t)16384 * 1024;
    unsigned short* wvb    = wqkT + (size_t)1024 * 1024;
    unsigned short* qk     = wvb + (size_t)1024 * 1024;
    float*          partial= (float*)(qk + (size_t)16384 * 1024);
    float*          attn   = partial + (size_t)8 * 32 * 4096;
    unsigned short* weffT  = (unsigned short*)(attn + (size_t)32 * 4096);
    unsigned short* wfoldT = weffT + (size_t)2 * 1024 * 1024;

    cvt_x_kernel<<<16384, 256, 0, stream>>>(x, xb);
    cvt_x_kernel<<<1024, 256, 0, stream>>>(Wv, wvb);          // plain cvt
    cvt_wT_kernel<<<dim3(32, 32), dim3(32, 8), 0, stream>>>(Wqk, wqkT);

    // qk = x @ W_qk  (M=16384, N=1024, K=1024), bf16 out
    gemm_bt<1><<<dim3(8, 128, 1), 256, 0, stream>>>(
        xb, wqkT, (void*)qk, 1024, 1024, 1024, 1024, 0, 0, 0);

    gram_kernel<<<dim3(32, 8), 256, 0, stream>>>(qk, partial);
    softmax_kernel<<<512, 256, 0, stream>>>(partial, tau, attn);
    wefft_kernel<<<dim3(32, 16), 256, 0, stream>>>(attn, Wout, weffT);

    // WfoldT_b[j][c'] = sum_i WeffT_b[j][i] * W_v[c'][i]  (bf16 out)
    gemm_bt<1><<<dim3(8, 8, 2), 256, 0, stream>>>(
        weffT, wvb, (void*)wfoldT, 1024, 1024, 1024, 1024,
        (size_t)1024 * 1024, 0, (size_t)1024 * 1024);

    // out_b = x_b @ Wfold_b  (M=8192, N=1024, K=1024), fp32 out
    gemm_bt<0><<<dim3(8, 64, 2), 256, 0, stream>>>(
        xb, wfoldT, d_out, 1024, 1024, 1024, 1024,
        (size_t)8192 * 1024, (size_t)1024 * 1024, (size_t)8192 * 1024);
}

// Round 4
// 266.547 us; speedup vs baseline: 1.2380x; 1.0537x over previous
//
#include <hip/hip_runtime.h>
#include <hip/hip_bf16.h>
#include <cstdint>
#include <cstddef>

// MFMA fragment types (gfx950: V8y operands, V4f accumulator)
typedef __bf16 v8bf __attribute__((ext_vector_type(8)));
typedef float  v4f  __attribute__((ext_vector_type(4)));

__device__ __forceinline__ unsigned short f2bf(float f) {
    unsigned int u = __float_as_uint(f);
    u += 0x7fffu + ((u >> 16) & 1u);   // round-to-nearest-even
    return (unsigned short)(u >> 16);
}

// async global->LDS, 16B per lane. LDS deposit is wave-uniform base + lane*16.
__device__ __forceinline__ void gload_lds16(const unsigned short* g, unsigned short* l) {
    __builtin_amdgcn_global_load_lds(
        (const __attribute__((address_space(1))) unsigned int*)(uintptr_t)g,
        (__attribute__((address_space(3))) unsigned int*)(uintptr_t)l, 16, 0, 0);
}

// ---------------------------------------------------------------------------
// GEMM: C[M,N] = A[M,K] * B[K,N], B transposed (BT is N x K). bf16 in, fp32 acc.
// 128x128 tile, 256 thr (4 waves x 64x64), BK=32, global_load_lds staging,
// XOR-swizzled LDS (4-way instead of 8-way ds_read_b128 conflicts).
// XCD-aware 1-D grid: dispatch is round-robin over 8 XCDs (id%8), so XCD k
// owns a contiguous M-range and its consecutive blocks share the A-strip
// (L2-hot) while B stays resident in that XCD's L2.
//   id -> xcd = id&7; s = id>>3; z = s/(mPerXcd*nBlk); s' = s%(mPerXcd*nBlk);
//   m = xcd*mPerXcd + s'/nBlk; n = s'%nBlk.
// ---------------------------------------------------------------------------
template<int WRITE_BF16>
__global__ __launch_bounds__(256, 2) void gemm_bt(
    const unsigned short* __restrict__ A,   // M x K, row stride lda (bf16)
    const unsigned short* __restrict__ BT,  // N x K, row stride ldb (bf16)
    void* __restrict__ C,                   // M x N, row stride ldc
    int K, int lda, int ldb, int ldc,
    size_t sAz, size_t sBz, size_t sCz,     // per-z strides (elements)
    int nBlk, int mPerXcd)
{
    __shared__ unsigned short sA[128 * 32];
    __shared__ unsigned short sB[128 * 32];

    const int id = blockIdx.x;
    const int xcd = id & 7;
    int s = id >> 3;
    const int perXcd = mPerXcd * nBlk;
    const int z = s / perXcd;
    s -= z * perXcd;
    const int mB = xcd * mPerXcd + s / nBlk;
    const int nB = s - (s / nBlk) * nBlk;

    const unsigned short* Ab = A + (size_t)z * sAz;
    const unsigned short* Bb = BT + (size_t)z * sBz;

    const int tid  = threadIdx.x;
    const int wv   = tid >> 6;
    const int lane = tid & 63;
    const int quad = lane >> 4;
    const int l16  = lane & 15;
    const size_t bm = (size_t)mB * 128;
    const size_t bn = (size_t)nB * 128;
    const int wm = (wv >> 1) * 64;
    const int wn = (wv & 1) * 64;

    // staging: thread tid -> LDS bytes [tid*16, tid*16+16) => row ro=tid>>2,
    // slot tid&3; source chunk XOR-swizzled: ko = ((tid&3)^(ro&3))*8.
    const int ro = tid >> 2;
    const int ko = (((tid & 3) ^ (ro & 3)) << 3);

    const unsigned short* aptr0 = Ab + (bm + ro)      * (size_t)lda + ko;
    const unsigned short* aptr1 = Ab + (bm + ro + 64) * (size_t)lda + ko;
    const unsigned short* bptr0 = Bb + (bn + ro)      * (size_t)ldb + ko;
    const unsigned short* bptr1 = Bb + (bn + ro + 64) * (size_t)ldb + ko;

    unsigned short* sA0 = &sA[wv * 512];
    unsigned short* sA1 = &sA[2048 + wv * 512];
    unsigned short* sB0 = &sB[wv * 512];
    unsigned short* sB1 = &sB[2048 + wv * 512];

    // fragment read slot (un-swizzle): fragment row ..+l16 has row&3 == l16&3
    const int sslot = ((quad ^ (l16 & 3)) << 3);

    v4f acc[4][4] = {};

    for (int k0 = 0; k0 < K; k0 += 32) {
        gload_lds16(aptr0 + k0, sA0);
        gload_lds16(aptr1 + k0, sA1);
        gload_lds16(bptr0 + k0, sB0);
        gload_lds16(bptr1 + k0, sB1);
        __syncthreads();

        v8bf af[4], bfr[4];
        #pragma unroll
        for (int t = 0; t < 4; t++) {
            af[t]  = *(const v8bf*)&sA[(size_t)(wm + t * 16 + l16) * 32 + sslot];
            bfr[t] = *(const v8bf*)&sB[(size_t)(wn + t * 16 + l16) * 32 + sslot];
        }

        #pragma unroll
        for (int ti = 0; ti < 4; ti++)
            #pragma unroll
            for (int tj = 0; tj < 4; tj++)
                acc[ti][tj] = __builtin_amdgcn_mfma_f32_16x16x32_bf16(
                    af[ti], bfr[tj], acc[ti][tj], 0, 0, 0);
        __syncthreads();
    }

    if (WRITE_BF16) {
        unsigned short* Cb = (unsigned short*)C + (size_t)z * sCz;
        #pragma unroll
        for (int ti = 0; ti < 4; ti++) {
            const size_t row0 = bm + wm + ti * 16 + quad * 4;
            #pragma unroll
            for (int tj = 0; tj < 4; tj++) {
                const size_t col = bn + wn + tj * 16 + l16;
                #pragma unroll
                for (int r = 0; r < 4; r++)
                    Cb[(row0 + r) * (size_t)ldc + col] = f2bf(acc[ti][tj][r]);
            }
        }
    } else {
        float* Cb = (float*)C + (size_t)z * sCz;
        #pragma unroll
        for (int ti = 0; ti < 4; ti++) {
            const size_t row0 = bm + wm + ti * 16 + quad * 4;
            #pragma unroll
            for (int tj = 0; tj < 4; tj++) {
                const size_t col = bn + wn + tj * 16 + l16;
                #pragma unroll
                for (int r = 0; r < 4; r++)
                    Cb[(row0 + r) * (size_t)ldc + col] = acc[ti][tj][r];
            }
        }
    }
}

// ---------------------------------------------------------------------------
// Gram via MFMA: partial[split][bh][c][d] = sum_{n in split} M[n][c]*M[n][d],
// M = qk head slice (tokens x 64 ch), row stride 1024. 16 splits x 512 tokens,
// 4 chunks of 128 with register prefetch across the barrier.
// ---------------------------------------------------------------------------
__global__ __launch_bounds__(256) void gram_kernel(
    const unsigned short* __restrict__ qk,   // 16384 x 1024 bf16
    float* __restrict__ partial)             // [16][32][64][64]
{
    const int bh = blockIdx.x;               // b*16+h
    const int split = blockIdx.y;            // 0..15
    const int b = bh >> 4, h = bh & 15;
    const unsigned short* base = qk + (size_t)b * 8192 * 1024 + (size_t)h * 64;
    const int n0 = split * 512;

    __shared__ unsigned short sMT[64 * 136]; // [ch][tok], stride 136
    const int tid = threadIdx.x;
    const int wv = tid >> 6, lane = tid & 63, quad = lane >> 4, l16 = lane & 15;

    // thread's staging element: ch = tid + i*256 -> tok = ch>>3, co = (ch&7)*8
    uint4 pre[4];
    #pragma unroll
    for (int i = 0; i < 4; i++) {
        const int ch = tid + i * 256, tok = ch >> 3, co = (ch & 7) << 3;
        pre[i] = *(const uint4*)(base + (size_t)(n0 + tok) * 1024 + co);
    }

    v4f acc[4] = {};

    for (int chunk = 0; chunk < 4; chunk++) {
        __syncthreads();   // previous chunk's LDS reads done
        #pragma unroll
        for (int i = 0; i < 4; i++) {
            const int ch = tid + i * 256, tok = ch >> 3, co = (ch & 7) << 3;
            union { uint4 v; unsigned short s8[8]; } u; u.v = pre[i];
            #pragma unroll
            for (int j = 0; j < 8; j++)
                sMT[(size_t)(co + j) * 136 + tok] = u.s8[j];
        }
        __syncthreads();

        if (chunk < 3) {   // issue next chunk's loads; waitcnt lands next iter
            const int nb = n0 + (chunk + 1) * 128;
            #pragma unroll
            for (int i = 0; i < 4; i++) {
                const int ch = tid + i * 256, tok = ch >> 3, co = (ch & 7) << 3;
                pre[i] = *(const uint4*)(base + (size_t)(nb + tok) * 1024 + co);
            }
        }

        #pragma unroll
        for (int ks = 0; ks < 4; ks++) {
            const int kb = ks * 32 + quad * 8;
            const v8bf a = *(const v8bf*)&sMT[(size_t)(16 * wv + l16) * 136 + kb];
            #pragma unroll
            for (int t = 0; t < 4; t++) {
                const v8bf bb = *(const v8bf*)&sMT[(size_t)(t * 16 + l16) * 136 + kb];
                acc[t] = __builtin_amdgcn_mfma_f32_16x16x32_bf16(a, bb, acc[t], 0, 0, 0);
            }
        }
    }

    float* outp = partial + ((size_t)split * 32 + bh) * 4096;
    #pragma unroll
    for (int t = 0; t < 4; t++)
        #pragma unroll
        for (int r = 0; r < 4; r++)
            outp[(size_t)(16 * wv + quad * 4 + r) * 64 + t * 16 + l16] = acc[t][r];
}

// ---------------------------------------------------------------------------
// Softmax: one wave per (bh, c) row over d (64 lanes). Writes TRANSPOSED
// attnT[bh][d][c] so wefft can load without an LDS transpose.
// ---------------------------------------------------------------------------
__global__ __launch_bounds__(256) void softmax_kernel(
    const float* __restrict__ partial,   // [16][32][4096]
    const float* __restrict__ tau,       // [16]
    float* __restrict__ attnT)           // [32][64(d)][64(c)]
{
    const int gw = (int)((blockIdx.x * 256 + threadIdx.x) >> 6);  // 0..2047
    const int d = threadIdx.x & 63;
    const int bh = gw >> 6;
    const int c = gw & 63;
    const int h = bh & 15;

    float cd = 0.f, cc = 0.f, dd = 0.f;
    #pragma unroll
    for (int s = 0; s < 16; s++) {
        const float* p = partial + ((size_t)s * 32 + bh) * 4096;
        cd += p[c * 64 + d];
        cc += p[c * 65];
        dd += p[d * 65];
    }
    const float INV_SQRT_N = 0.011048543456039806f;  // 1/sqrt(8192)
    const float logit = (2.f * cd - cc - dd) * INV_SQRT_N * tau[h];

    float m = logit;
    #pragma unroll
    for (int off = 32; off > 0; off >>= 1) m = fmaxf(m, __shfl_xor(m, off, 64));
    const float e = __expf(logit - m);
    float sum = e;
    #pragma unroll
    for (int off = 32; off > 0; off >>= 1) sum += __shfl_xor(sum, off, 64);

    attnT[(size_t)bh * 4096 + d * 64 + c] = e / sum;
}

// ---------------------------------------------------------------------------
// WeffT[b][j][h*64+d] = sum_c attn[b,h,c,d] * W_out[h*64+c, j]   (bf16 out)
// ---------------------------------------------------------------------------
__global__ __launch_bounds__(256) void wefft_kernel(
    const float* __restrict__ attnT,      // [32][64(d)][64(c)]
    const float* __restrict__ Wout,       // [1024][1024] fp32
    unsigned short* __restrict__ weffT)   // [2][1024][1024] bf16 (j, i)
{
    const int bh = blockIdx.x;            // 0..31
    const int jg = blockIdx.y;            // 0..15
    const int b = bh >> 4, h = bh & 15;

    __shared__ float sAttT[64][65];       // [d][c]
    __shared__ float sW[64][65];          // [c][j_local]
    const int tid = threadIdx.x;
    const float* ap = attnT + (size_t)bh * 4096;
    const float* wp = Wout + (size_t)(h * 64) * 1024 + jg * 64;
    for (int i = tid; i < 4096; i += 256) {
        const int r = i >> 6, q = i & 63;
        sAttT[r][q] = ap[i];              // already transposed in global
        sW[r][q] = wp[(size_t)r * 1024 + q];
    }
    __syncthreads();

    const int dd0 = (tid >> 4) << 2;
    const int j0  = (tid & 15) << 2;
    float acc[4][4] = {};
    for (int cc = 0; cc < 64; cc++) {
        float av[4], wvv[4];
        #pragma unroll
        for (int i = 0; i < 4; i++) av[i] = sAttT[dd0 + i][cc];
        #pragma unroll
        for (int i = 0; i < 4; i++) wvv[i] = sW[cc][j0 + i];
        #pragma unroll
        for (int i = 0; i < 4; i++)
            #pragma unroll
            for (int j = 0; j < 4; j++)
                acc[i][j] += av[i] * wvv[j];
    }

    unsigned short* op = weffT + ((size_t)b * 1024 + jg * 64) * 1024 + h * 64;
    #pragma unroll
    for (int i = 0; i < 4; i++)
        #pragma unroll
        for (int j = 0; j < 4; j++)
            op[(size_t)(j0 + j) * 1024 + dd0 + i] = f2bf(acc[i][j]);
}

// ---------------------------------------------------------------------------
// Fused conversions: x -> bf16 (16384 blks), Wv -> bf16 (1024 blks),
// Wqk -> transposed bf16 (1024 tile blks). One dispatch.
// ---------------------------------------------------------------------------
__global__ __launch_bounds__(256) void cvt_all_kernel(
    const float* __restrict__ x, const float* __restrict__ Wv,
    const float* __restrict__ Wqk,
    unsigned short* __restrict__ xb, unsigned short* __restrict__ wvb,
    unsigned short* __restrict__ wqkT)
{
    const int bid = blockIdx.x;
    if (bid < 17408) {
        const float* src = (bid < 16384) ? x : Wv;
        unsigned short* dst = (bid < 16384) ? xb : wvb;
        const size_t blk = (bid < 16384) ? bid : (bid - 16384);
        const size_t i = (blk * 256 + threadIdx.x) * 4;
        const float4 v = *(const float4*)(src + i);
        ushort4 o;
        o.x = f2bf(v.x); o.y = f2bf(v.y); o.z = f2bf(v.z); o.w = f2bf(v.w);
        *(ushort4*)(dst + i) = o;
    } else {
        const int t = bid - 17408;
        const int n0 = (t & 31) * 32, k0 = (t >> 5) * 32;
        __shared__ float sT[32][33];
        const int tx = threadIdx.x & 31, ty = threadIdx.x >> 5;
        #pragma unroll
        for (int i = ty; i < 32; i += 8)
            sT[i][tx] = Wqk[(size_t)(k0 + i) * 1024 + n0 + tx];
        __syncthreads();
        #pragma unroll
        for (int i = ty; i < 32; i += 8)
            wqkT[(size_t)(n0 + i) * 1024 + k0 + tx] = f2bf(sT[tx][i]);
    }
}

// ---------------------------------------------------------------------------
extern "C" void kernel_launch(void* const* d_in, const int* in_sizes, int n_in,
                              void* d_out, int out_size, void* d_ws, size_t ws_size,
                              hipStream_t stream)
{
    (void)in_sizes; (void)n_in; (void)out_size; (void)ws_size;
    const float* x    = (const float*)d_in[0];
    const float* Wqk  = (const float*)d_in[1];
    const float* Wv   = (const float*)d_in[2];
    const float* Wout = (const float*)d_in[3];
    const float* tau  = (const float*)d_in[4];

    // out_b = x_b @ (W_v @ Weff_b); v never materialized.
    // ws layout:
    //   xb     : 16384x1024  bf16 (32 MB)
    //   wqkT   : 1024x1024   bf16 ( 2 MB)
    //   wvb    : 1024x1024   bf16 ( 2 MB)
    //   qk     : 16384x1024  bf16 (32 MB)
    //   partial: 16x32x4096  f32  ( 8 MB)
    //   attnT  : 32x4096     f32  (.5 MB)
    //   weffT  : 2x1024x1024 bf16 ( 4 MB)
    //   wfoldT : 2x1024x1024 bf16 ( 4 MB)
    unsigned short* xb     = (unsigned short*)d_ws;
    unsigned short* wqkT   = xb + (size_t)16384 * 1024;
    unsigned short* wvb    = wqkT + (size_t)1024 * 1024;
    unsigned short* qk     = wvb + (size_t)1024 * 1024;
    float*          partial= (float*)(qk + (size_t)16384 * 1024);
    float*          attnT  = partial + (size_t)16 * 32 * 4096;
    unsigned short* weffT  = (unsigned short*)(attnT + (size_t)32 * 4096);
    unsigned short* wfoldT = weffT + (size_t)2 * 1024 * 1024;

    cvt_all_kernel<<<18432, 256, 0, stream>>>(x, Wv, Wqk, xb, wvb, wqkT);

    // qk = x @ W_qk  (M=16384, N=1024, K=1024): 128 m-blks, 8 n-blks
    gemm_bt<1><<<1024, 256, 0, stream>>>(
        xb, wqkT, (void*)qk, 1024, 1024, 1024, 1024, 0, 0, 0, 8, 16);

    gram_kernel<<<dim3(32, 16), 256, 0, stream>>>(qk, partial);
    softmax_kernel<<<512, 256, 0, stream>>>(partial, tau, attnT);
    wefft_kernel<<<dim3(32, 16), 256, 0, stream>>>(attnT, Wout, weffT);

    // WfoldT_b[j][c'] = sum_i WeffT_b[j][i] * W_v[c'][i]: 8 m-blks, 8 n, z=2
    gemm_bt<1><<<128, 256, 0, stream>>>(
        weffT, wvb, (void*)wfoldT, 1024, 1024, 1024, 1024,
        (size_t)1024 * 1024, 0, (size_t)1024 * 1024, 8, 1);

    // out_b = x_b @ Wfold_b  (M=8192/z, N=1024, K=1024): 64 m-blks, 8 n, z=2
    gemm_bt<0><<<1024, 256, 0, stream>>>(
        xb, wfoldT, d_out, 1024, 1024, 1024, 1024,
        (size_t)8192 * 1024, (size_t)1024 * 1024, (size_t)8192 * 1024, 8, 8);
}